// Round 5
// baseline (1019.606 us; speedup 1.0000x reference)
//
#include <hip/hip_runtime.h>

typedef __bf16 bf16_t;
typedef bf16_t bf16x2_t __attribute__((ext_vector_type(2)));
typedef bf16_t bf16x8_t __attribute__((ext_vector_type(8)));
typedef float  f32x4_t  __attribute__((ext_vector_type(4)));

#define RCHUNK 4096
#define MFMA16(a, b, c) __builtin_amdgcn_mfma_f32_16x16x32_bf16((a), (b), (c), 0, 0, 0)

// ---------------------------------------------------------------------------
// Weight packing: W[t][k0+k][n] (f32, row-stride 128) -> bf16 MFMA-B-fragment
// order: out[((t*KB+kb)*8+nb)*512 + l*8 + j] = W[t][k0+kb*32+(l>>4)*8+j][nb*16+(l&15)]
// ---------------------------------------------------------------------------
__global__ void pack_w_kernel(const float* __restrict__ W, bf16_t* __restrict__ out,
                              int T, int Ksrc, int k0, int KB)
{
  int total = T * KB * 8 * 512;
  for (int idx = blockIdx.x * blockDim.x + threadIdx.x; idx < total;
       idx += gridDim.x * blockDim.x) {
    int j  = idx & 7;
    int l  = (idx >> 3) & 63;
    int nb = (idx >> 9) & 7;
    int r  = idx >> 12;
    int kb = r % KB;
    int t  = r / KB;
    int k = k0 + kb * 32 + ((l >> 4) << 3) + j;
    int n = nb * 16 + (l & 15);
    out[idx] = (bf16_t)W[((size_t)t * Ksrc + k) * 128 + n];
  }
}

// ---------------------------------------------------------------------------
// Stable counting-sort rank/perm over a small type alphabet T.
// ---------------------------------------------------------------------------
template <int T>
__global__ void count_types_kernel(const int* __restrict__ tv, int n,
                                   int* __restrict__ blkcnt)
{
  __shared__ int cnt[T];
  int tid = threadIdx.x, b = blockIdx.x;
  if (tid < T) cnt[tid] = 0;
  __syncthreads();
  int lo = b * RCHUNK, hi = min(n, lo + RCHUNK);
  int loc[T];
#pragma unroll
  for (int t = 0; t < T; ++t) loc[t] = 0;
  for (int i = lo + tid; i < hi; i += 256) {
    int tq = tv[i];
#pragma unroll
    for (int t = 0; t < T; ++t) loc[t] += (tq == t);
  }
#pragma unroll
  for (int t = 0; t < T; ++t)
    if (loc[t]) atomicAdd(&cnt[t], loc[t]);
  __syncthreads();
  if (tid < T) blkcnt[b * T + tid] = cnt[tid];
}

template <int T>
__global__ void scan_blocks_kernel(const int* __restrict__ blkcnt, int nblocks,
                                   int* __restrict__ blkbase)
{
  __shared__ int sh[256];
  __shared__ int tot[T];
  int tid = threadIdx.x;
  int myc[T], excl[T];
#pragma unroll
  for (int t = 0; t < T; ++t) myc[t] = (tid < nblocks) ? blkcnt[tid * T + t] : 0;
#pragma unroll
  for (int t = 0; t < T; ++t) {
    sh[tid] = myc[t];
    __syncthreads();
    for (int off = 1; off < 256; off <<= 1) {
      int v = (tid >= off) ? sh[tid - off] : 0;
      __syncthreads();
      sh[tid] += v;
      __syncthreads();
    }
    excl[t] = sh[tid] - myc[t];
    if (tid == 255) tot[t] = sh[255];
    __syncthreads();
  }
  if (tid < nblocks) {
    int run = 0;
#pragma unroll
    for (int t = 0; t < T; ++t) {
      blkbase[tid * T + t] = run + excl[t];
      run += tot[t];
    }
  }
}

template <int T>
__global__ void write_ranks_kernel(const int* __restrict__ tv, int n,
                                   const int* __restrict__ blkbase,
                                   int* __restrict__ rank, int* __restrict__ perm)
{
  __shared__ int sh[256];
  int tid = threadIdx.x, b = blockIdx.x;
  int lo = b * RCHUNK + tid * 16;
  int tvq[16];
  int myc[T];
#pragma unroll
  for (int t = 0; t < T; ++t) myc[t] = 0;
#pragma unroll
  for (int q = 0; q < 16; ++q) {
    int i = lo + q;
    int tq = (i < n) ? tv[i] : -1;
    tvq[q] = tq;
#pragma unroll
    for (int t = 0; t < T; ++t) myc[t] += (tq == t);
  }
  int mybase[T];
#pragma unroll
  for (int t = 0; t < T; ++t) {
    sh[tid] = myc[t];
    __syncthreads();
    for (int off = 1; off < 256; off <<= 1) {
      int v = (tid >= off) ? sh[tid - off] : 0;
      __syncthreads();
      sh[tid] += v;
      __syncthreads();
    }
    mybase[t] = blkbase[b * T + t] + sh[tid] - myc[t];
    __syncthreads();
  }
#pragma unroll
  for (int q = 0; q < 16; ++q) {
    int tq = tvq[q];
    if (tq < 0) continue;
    int r = 0;
#pragma unroll
    for (int t = 0; t < T; ++t)
      if (tq == t) { r = mybase[t]; mybase[t] = r + 1; }
    rank[lo + q] = r;
    perm[r] = lo + q;
  }
}

// ---------------------------------------------------------------------------
// dst-CSR: histogram -> single-block scan -> atomic-cursor position assign.
// dstpos[j] = slot of final-edge j in dst-grouped order.
// ---------------------------------------------------------------------------
__global__ void hist_dst_kernel(const int* __restrict__ dst, int E,
                                int* __restrict__ hist)
{
  int i = blockIdx.x * blockDim.x + threadIdx.x;
  if (i < E) atomicAdd(&hist[dst[i]], 1);
}

__global__ __launch_bounds__(1024) void scan_offsets_kernel(
    const int* __restrict__ hist, int n, int* __restrict__ offsets,
    int* __restrict__ cursor)
{
  __shared__ int sh[1024];
  int tid = threadIdx.x;
  int per = (n + 1023) >> 10;
  int lo = tid * per;
  int s = 0;
  for (int q = 0; q < per; ++q) {
    int i = lo + q;
    if (i < n) s += hist[i];
  }
  sh[tid] = s;
  __syncthreads();
  for (int off = 1; off < 1024; off <<= 1) {
    int v = (tid >= off) ? sh[tid - off] : 0;
    __syncthreads();
    sh[tid] += v;
    __syncthreads();
  }
  int run = sh[tid] - s;
  for (int q = 0; q < per; ++q) {
    int i = lo + q;
    if (i < n) {
      offsets[i] = run;
      cursor[i] = run;
      run += hist[i];
    }
  }
  if (tid == 1023) offsets[n] = sh[1023];
}

__global__ void scatter_dst_kernel(const int* __restrict__ dst, int E,
                                   int* __restrict__ cursor,
                                   int* __restrict__ dstpos)
{
  int i = blockIdx.x * blockDim.x + threadIdx.x;
  if (i < E) dstpos[i] = atomicAdd(&cursor[dst[i]], 1);
}

// ---------------------------------------------------------------------------
// Flattened per-position meta: meta4[pos] = {e, src[e], dst[e], j=rank[pos]},
// slotv[pos] = dstpos[j].  (node variant: {e,e,e,j})
// ---------------------------------------------------------------------------
__global__ void gather_meta_edge_kernel(const int* __restrict__ perm,
                                        const int* __restrict__ rank,
                                        const int* __restrict__ src,
                                        const int* __restrict__ dst,
                                        const int* __restrict__ dstpos,
                                        int4* __restrict__ meta4,
                                        int* __restrict__ slotv, int E)
{
  int i = blockIdx.x * blockDim.x + threadIdx.x;
  if (i < E) {
    int e = perm[i], j = rank[i];
    int4 m;
    m.x = e; m.y = src[e]; m.z = dst[e]; m.w = j;
    meta4[i] = m;
    slotv[i] = dstpos[j];
  }
}

__global__ void gather_meta_node_kernel(const int* __restrict__ perm,
                                        const int* __restrict__ rank,
                                        int4* __restrict__ meta4, int N)
{
  int i = blockIdx.x * blockDim.x + threadIdx.x;
  if (i < N) {
    int e = perm[i];
    int4 m;
    m.x = e; m.y = e; m.z = e; m.w = rank[i];
    meta4[i] = m;
  }
}

// ---------------------------------------------------------------------------
// Sequential slot aggregation: agg[n] = sum of slot_buf rows [off[n],off[n+1]).
// One wave per node; lane = 2 bf16 cols; streaming CSR-contiguous reads.
// ---------------------------------------------------------------------------
__global__ __launch_bounds__(256) void aggregate_slots_kernel(
    const bf16_t* __restrict__ slot_buf, const int* __restrict__ offsets,
    float* __restrict__ agg, int Nn)
{
  int gw = (blockIdx.x * 256 + threadIdx.x) >> 6;
  int l = threadIdx.x & 63;
  int nw = (gridDim.x * 256) >> 6;
  for (int n = gw; n < Nn; n += nw) {
    int lo = offsets[n], hi = offsets[n + 1];
    float sx = 0.f, sy = 0.f;
    int q = lo;
    for (; q + 1 < hi; q += 2) {
      bf16x2_t v0 = *(const bf16x2_t*)(slot_buf + (size_t)q * 128 + l * 2);
      bf16x2_t v1 = *(const bf16x2_t*)(slot_buf + (size_t)(q + 1) * 128 + l * 2);
      sx += (float)v0[0] + (float)v1[0];
      sy += (float)v0[1] + (float)v1[1];
    }
    if (q < hi) {
      bf16x2_t v0 = *(const bf16x2_t*)(slot_buf + (size_t)q * 128 + l * 2);
      sx += (float)v0[0];
      sy += (float)v0[1];
    }
    float2 o; o.x = sx; o.y = sy;
    *(float2*)(agg + (size_t)n * 128 + l * 2) = o;
  }
}

// ---------------------------------------------------------------------------
// P precompute (persistent): 8 slots x nseg blocks; W staged once per block.
// ---------------------------------------------------------------------------
__global__ __launch_bounds__(256) void precompute_p_kernel(
    const float* __restrict__ nf,
    const bf16_t* __restrict__ pW1s, const bf16_t* __restrict__ pW1d,
    const bf16_t* __restrict__ pWn1b,
    bf16_t* __restrict__ Ps, bf16_t* __restrict__ Pd, bf16_t* __restrict__ Pn,
    int Nn, int nseg)
{
  __shared__ char Wsm[32768];
  const int which = blockIdx.x & 7;
  const int seg = blockIdx.x >> 3;
  const bf16_t* pB; bf16_t* po;
  if (which < 3)      { pB = pW1s + which * 16384;        po = Ps + (size_t)which * Nn * 128; }
  else if (which < 6) { pB = pW1d + (which - 3) * 16384;  po = Pd + (size_t)(which - 3) * Nn * 128; }
  else                { pB = pWn1b + (which - 6) * 16384; po = Pn + (size_t)(which - 6) * Nn * 128; }

  const int tid = threadIdx.x, l = tid & 63, w = tid >> 6;
  const int rb = (w >> 1) * 32, cb = (w & 1) * 64, l15 = l & 15;
  const int koff = (l >> 4) << 3;

  {
    const uint4* g = (const uint4*)pB;
    uint4* d = (uint4*)Wsm;
#pragma unroll
    for (int q = 0; q < 8; ++q) d[q * 256 + tid] = g[q * 256 + tid];
  }
  __syncthreads();

  const int ntiles = (Nn + 63) >> 6;
  for (int tile = seg; tile < ntiles; tile += nseg) {
    const int base = tile * 64;
    const int r0 = min(base + rb + l15, Nn - 1);
    const int r1 = min(base + rb + l15 + 16, Nn - 1);
    const float* q0 = nf + (size_t)r0 * 128 + koff;
    const float* q1 = nf + (size_t)r1 * 128 + koff;
    f32x4_t areg[16];
#pragma unroll
    for (int kb = 0; kb < 4; ++kb) {
      areg[kb * 2]     = ((const f32x4_t*)(q0 + kb * 32))[0];
      areg[kb * 2 + 1] = ((const f32x4_t*)(q0 + kb * 32))[1];
      areg[8 + kb * 2]     = ((const f32x4_t*)(q1 + kb * 32))[0];
      areg[8 + kb * 2 + 1] = ((const f32x4_t*)(q1 + kb * 32))[1];
    }
    f32x4_t acc[2][4];
#pragma unroll
    for (int m = 0; m < 2; ++m)
#pragma unroll
      for (int n = 0; n < 4; ++n) acc[m][n] = (f32x4_t){0.f, 0.f, 0.f, 0.f};
#pragma unroll
    for (int kb = 0; kb < 4; ++kb) {
      bf16x8_t bfr[4];
#pragma unroll
      for (int n = 0; n < 4; ++n)
        bfr[n] = *(const bf16x8_t*)(Wsm + ((kb * 8 + (cb >> 4) + n) * 64 + l) * 16);
      bf16x8_t a0, a1;
#pragma unroll
      for (int z = 0; z < 4; ++z) {
        a0[z] = (bf16_t)areg[kb * 2][z];     a0[4 + z] = (bf16_t)areg[kb * 2 + 1][z];
        a1[z] = (bf16_t)areg[8 + kb * 2][z]; a1[4 + z] = (bf16_t)areg[8 + kb * 2 + 1][z];
      }
#pragma unroll
      for (int n = 0; n < 4; ++n) {
        acc[0][n] = MFMA16(a0, bfr[n], acc[0][n]);
        acc[1][n] = MFMA16(a1, bfr[n], acc[1][n]);
      }
    }
#pragma unroll
    for (int n = 0; n < 4; ++n) {
      int col = cb + 16 * n + l15;
#pragma unroll
      for (int m = 0; m < 2; ++m)
#pragma unroll
        for (int jj = 0; jj < 4; ++jj) {
          int row = rb + 16 * m + ((l >> 4) << 2) + jj;
          int node = base + row;
          if (node < Nn) po[(size_t)node * 128 + col] = (bf16_t)acc[m][n][jj];
        }
    }
  }
}

// ---------------------------------------------------------------------------
// Pipelined single-type-tile fused 2-layer MLP (K1=128 via P-precompute).
// Shuffle-routed meta (no LDS meta); A + Psum prefetched one tile ahead into
// registers; Psum staged in-place into Hsm (shared XOR swizzle); W1 LDS-
// resident, W2 register-resident; 3 barriers/tile; no atomics.
// Epilogue: f32 out[j] + bf16 slot_out[slot] (dst-CSR position).
// ---------------------------------------------------------------------------
template <int T, bool EDGE>
__global__ __launch_bounds__(256, 2) void mlp5_kernel(
    const float* __restrict__ feat,
    const int4* __restrict__ meta4, const int* __restrict__ slotv,
    const int* __restrict__ tbase,
    const bf16_t* __restrict__ pW1, const float* __restrict__ b1,
    const bf16_t* __restrict__ pW2, const float* __restrict__ b2,
    const bf16_t* __restrict__ P1, const bf16_t* __restrict__ P2, int pnodes,
    float* __restrict__ out, bf16_t* __restrict__ slot_out, int Ntot)
{
  __shared__ char Wsm[32768];
  __shared__ char Hsm[16384];

  const int tid = threadIdx.x;
  const int l = tid & 63, w = tid >> 6;
  const int rb = (w >> 1) * 32, cb = (w & 1) * 64;
  const int l15 = l & 15;
  const int koff = (l >> 4) << 3;

  const int s0 = tbase[0];
  const int s1 = (T > 1) ? tbase[1] : Ntot;
  const int s2 = (T > 2) ? tbase[2] : Ntot;
  const int e0t = (T > 1) ? s1 : Ntot;
  const int e1t = (T > 2) ? s2 : Ntot;
  const int c0 = (e0t - s0 + 63) >> 6;
  const int c1 = (T > 1) ? ((e1t - s1 + 63) >> 6) : 0;
  const int c2 = (T > 2) ? ((Ntot - s2 + 63) >> 6) : 0;
  const int cum1 = c0, cum2 = c0 + c1, total = cum2 + c2;

  const int tpb = (total + gridDim.x - 1) / gridDim.x;
  const int pt0 = blockIdx.x * tpb;
  const int pt1 = min(total, pt0 + tpb);
  if (pt0 >= pt1) return;

  auto tinfo_t = [&](int pt) -> int {
    return (pt < cum1) ? 0 : ((pt < cum2) ? 1 : 2);
  };
  auto tinfo_base = [&](int pt) -> int {
    return (pt < cum1) ? s0 + (pt << 6)
         : (pt < cum2) ? s1 + ((pt - cum1) << 6)
                       : s2 + ((pt - cum2) << 6);
  };
  auto tinfo_end = [&](int pt) -> int {
    return (pt < cum1) ? e0t : ((pt < cum2) ? e1t : Ntot);
  };
  auto load_meta = [&](int pt, int4& m, int& sl) {
    int pos = tinfo_base(pt) + l;
    int p = min(pos, Ntot - 1);
    m = meta4[p];
    if (EDGE) sl = slotv[p];
    if (pos >= tinfo_end(pt)) m.w = -1;
  };

  const int prow = (w << 4) + (l >> 2);   // psum staging row (16 rows/wave)
  const int pcb  = (l & 3) << 2;          // psum chunk base (4 x 16B chunks)

  int4 m_cur, m_nxt;
  int sl_cur = 0, sl_nxt = 0;
  f32x4_t Af[16];
  bf16x8_t uP[4], vP[4], ps[4];
  bf16x8_t w2r[16];
  float bh[4], bo[4];
  int t_cur = -1;

  // ---------------- prologue: tile pt0's A + Psum, meta(pt0+1) ----------------
  load_meta(pt0, m_cur, sl_cur);
  {
    int e0 = __shfl(m_cur.x, rb + l15);
    int e1 = __shfl(m_cur.x, rb + l15 + 16);
    const float* q0 = feat + (size_t)e0 * 128 + koff;
    const float* q1 = feat + (size_t)e1 * 128 + koff;
#pragma unroll
    for (int kb = 0; kb < 4; ++kb) {
      Af[kb * 2]     = ((const f32x4_t*)(q0 + kb * 32))[0];
      Af[kb * 2 + 1] = ((const f32x4_t*)(q0 + kb * 32))[1];
      Af[8 + kb * 2]     = ((const f32x4_t*)(q1 + kb * 32))[0];
      Af[8 + kb * 2 + 1] = ((const f32x4_t*)(q1 + kb * 32))[1];
    }
    int t0 = tinfo_t(pt0);
    int a = __shfl(EDGE ? m_cur.y : m_cur.x, prow);
    const bf16x8_t* pu = (const bf16x8_t*)(P1 + ((size_t)t0 * pnodes + a) * 128);
#pragma unroll
    for (int q = 0; q < 4; ++q) uP[q] = pu[pcb + q];
    if (EDGE) {
      int bi = __shfl(m_cur.z, prow);
      const bf16x8_t* pv = (const bf16x8_t*)(P2 + ((size_t)t0 * pnodes + bi) * 128);
#pragma unroll
      for (int q = 0; q < 4; ++q) vP[q] = pv[pcb + q];
    }
  }
  if (EDGE) {
#pragma unroll
    for (int q = 0; q < 4; ++q)
#pragma unroll
      for (int z = 0; z < 8; ++z)
        ps[q][z] = (bf16_t)((float)uP[q][z] + (float)vP[q][z]);
  } else {
#pragma unroll
    for (int q = 0; q < 4; ++q) ps[q] = uP[q];
  }
  load_meta(min(pt0 + 1, pt1 - 1), m_nxt, sl_nxt);

  // ---------------- main pipelined loop ----------------
  for (int pt = pt0; pt < pt1; ++pt) {
    const int t = tinfo_t(pt);
    if (t != t_cur) {                  // rare: ~1-3x per block
      __syncthreads();
      {
        const uint4* g = (const uint4*)(pW1 + (size_t)t * 16384);
        uint4* d = (uint4*)Wsm;
#pragma unroll
        for (int q = 0; q < 8; ++q) d[q * 256 + tid] = g[q * 256 + tid];
      }
      {
        const bf16x8_t* g2 = (const bf16x8_t*)pW2;
#pragma unroll
        for (int kb = 0; kb < 4; ++kb)
#pragma unroll
          for (int n = 0; n < 4; ++n)
            w2r[kb * 4 + n] = g2[(size_t)((t * 4 + kb) * 8 + (cb >> 4) + n) * 64 + l];
      }
#pragma unroll
      for (int n = 0; n < 4; ++n) {
        bh[n] = b1[t * 128 + cb + 16 * n + l15];
        bo[n] = b2[t * 128 + cb + 16 * n + l15];
      }
      t_cur = t;
      __syncthreads();
    }

    // ---- cvt A(k), layer-1 MFMA ----
    f32x4_t acc[2][4];
#pragma unroll
    for (int m = 0; m < 2; ++m)
#pragma unroll
      for (int n = 0; n < 4; ++n) acc[m][n] = (f32x4_t){0.f, 0.f, 0.f, 0.f};
    bf16x8_t a0[4], a1[4];
#pragma unroll
    for (int kb = 0; kb < 4; ++kb)
#pragma unroll
      for (int z = 0; z < 4; ++z) {
        a0[kb][z]     = (bf16_t)Af[kb * 2][z];
        a0[kb][4 + z] = (bf16_t)Af[kb * 2 + 1][z];
        a1[kb][z]     = (bf16_t)Af[8 + kb * 2][z];
        a1[kb][4 + z] = (bf16_t)Af[8 + kb * 2 + 1][z];
      }
#pragma unroll
    for (int kb = 0; kb < 4; ++kb) {
      bf16x8_t bfr[4];
#pragma unroll
      for (int n = 0; n < 4; ++n)
        bfr[n] = *(const bf16x8_t*)(Wsm + ((kb * 8 + (cb >> 4) + n) * 64 + l) * 16);
#pragma unroll
      for (int n = 0; n < 4; ++n) {
        acc[0][n] = MFMA16(a0[kb], bfr[n], acc[0][n]);
        acc[1][n] = MFMA16(a1[kb], bfr[n], acc[1][n]);
      }
    }

    // ---- issue A(k+1) into freed f32 regs (off critical path) ----
    const int ptn = min(pt + 1, pt1 - 1);
    {
      int e0 = __shfl(m_nxt.x, rb + l15);
      int e1 = __shfl(m_nxt.x, rb + l15 + 16);
      const float* q0 = feat + (size_t)e0 * 128 + koff;
      const float* q1 = feat + (size_t)e1 * 128 + koff;
#pragma unroll
      for (int kb = 0; kb < 4; ++kb) {
        Af[kb * 2]     = ((const f32x4_t*)(q0 + kb * 32))[0];
        Af[kb * 2 + 1] = ((const f32x4_t*)(q0 + kb * 32))[1];
        Af[8 + kb * 2]     = ((const f32x4_t*)(q1 + kb * 32))[0];
        Af[8 + kb * 2 + 1] = ((const f32x4_t*)(q1 + kb * 32))[1];
      }
    }

    __syncthreads();                   // #1: all waves done with Hsm(k-1) reads

    // ---- stage Psum(k) into Hsm (in-place layout) ----
    {
      char* base = Hsm + prow * 256;
#pragma unroll
      for (int q = 0; q < 4; ++q)
        *(bf16x8_t*)(base + ((((pcb + q) << 4)) ^ ((prow & 7) << 4))) = ps[q];
    }

    // ---- issue Psum(k+1) gathers ----
    {
      int tn = tinfo_t(ptn);
      int a = __shfl(EDGE ? m_nxt.y : m_nxt.x, prow);
      const bf16x8_t* pu = (const bf16x8_t*)(P1 + ((size_t)tn * pnodes + a) * 128);
#pragma unroll
      for (int q = 0; q < 4; ++q) uP[q] = pu[pcb + q];
      if (EDGE) {
        int bi = __shfl(m_nxt.z, prow);
        const bf16x8_t* pv = (const bf16x8_t*)(P2 + ((size_t)tn * pnodes + bi) * 128);
#pragma unroll
        for (int q = 0; q < 4; ++q) vP[q] = pv[pcb + q];
      }
    }

    // ---- advance meta pipeline (k+2) ----
    const int4 m_use = m_cur;
    const int sl_use = sl_cur;
    m_cur = m_nxt; sl_cur = sl_nxt;
    load_meta(min(pt + 2, pt1 - 1), m_nxt, sl_nxt);

    __syncthreads();                   // #2: Psum staged

    // ---- relu in place: h = relu(acc + psum + b1) ----
#pragma unroll
    for (int n = 0; n < 4; ++n) {
      int col = cb + 16 * n + l15;
      int byte = col * 2;
#pragma unroll
      for (int m = 0; m < 2; ++m)
#pragma unroll
        for (int jj = 0; jj < 4; ++jj) {
          int row = rb + 16 * m + ((l >> 4) << 2) + jj;
          char* addr = Hsm + row * 256 + (byte ^ ((row & 7) << 4));
          float pv = (float)*(const bf16_t*)addr;
          float v = acc[m][n][jj] + pv + bh[n];
          v = v > 0.f ? v : 0.f;
          *(bf16_t*)addr = (bf16_t)v;
        }
    }

    __syncthreads();                   // #3: Hsm complete

    // ---- layer 2 ----
    f32x4_t acc2[2][4];
#pragma unroll
    for (int m = 0; m < 2; ++m)
#pragma unroll
      for (int n = 0; n < 4; ++n) acc2[m][n] = (f32x4_t){0.f, 0.f, 0.f, 0.f};
#pragma unroll
    for (int kb = 0; kb < 4; ++kb) {
      int kbyte = kb * 64 + ((l >> 4) << 4);
      int row0 = rb + l15, row1 = row0 + 16;
      bf16x8_t h0 = *(const bf16x8_t*)(Hsm + row0 * 256 + (kbyte ^ ((row0 & 7) << 4)));
      bf16x8_t h1 = *(const bf16x8_t*)(Hsm + row1 * 256 + (kbyte ^ ((row1 & 7) << 4)));
#pragma unroll
      for (int n = 0; n < 4; ++n) {
        acc2[0][n] = MFMA16(h0, w2r[kb * 4 + n], acc2[0][n]);
        acc2[1][n] = MFMA16(h1, w2r[kb * 4 + n], acc2[1][n]);
      }
    }

    // ---- epilogue: out[j] (f32) + slot_out[slot] (bf16) ----
    int jrow[2][4], srow[2][4];
#pragma unroll
    for (int m = 0; m < 2; ++m)
#pragma unroll
      for (int jj = 0; jj < 4; ++jj) {
        int row = rb + 16 * m + ((l >> 4) << 2) + jj;
        jrow[m][jj] = __shfl(m_use.w, row);
        srow[m][jj] = EDGE ? __shfl(sl_use, row) : 0;
      }
#pragma unroll
    for (int n = 0; n < 4; ++n) {
      int col = cb + 16 * n + l15;
#pragma unroll
      for (int m = 0; m < 2; ++m)
#pragma unroll
        for (int jj = 0; jj < 4; ++jj) {
          int j = jrow[m][jj];
          if (j >= 0) {
            float v = acc2[m][n][jj] + bo[n];
            out[(size_t)j * 128 + col] = v;
            if (EDGE) slot_out[(size_t)srow[m][jj] * 128 + col] = (bf16_t)v;
          }
        }
    }

    // ---- combine Psum(k+1) (waits its gathers here, after all overlap) ----
    if (EDGE) {
#pragma unroll
      for (int q = 0; q < 4; ++q)
#pragma unroll
        for (int z = 0; z < 8; ++z)
          ps[q][z] = (bf16_t)((float)uP[q][z] + (float)vP[q][z]);
    } else {
#pragma unroll
      for (int q = 0; q < 4; ++q) ps[q] = uP[q];
    }
  }
}

// ---------------------------------------------------------------------------
extern "C" void kernel_launch(void* const* d_in, const int* in_sizes, int n_in,
                              void* d_out, int out_size, void* d_ws, size_t ws_size,
                              hipStream_t stream)
{
  const float* nf    = (const float*)d_in[0];
  const float* ef    = (const float*)d_in[1];
  const int*   src   = (const int*)d_in[2];
  const int*   dst   = (const int*)d_in[3];
  const int*   etype = (const int*)d_in[4];
  const int*   ntype = (const int*)d_in[5];
  const float* Weh   = (const float*)d_in[6];
  const float* beh   = (const float*)d_in[7];
  const float* Weo   = (const float*)d_in[8];
  const float* beo   = (const float*)d_in[9];
  const float* Wnh   = (const float*)d_in[10];
  const float* bnh   = (const float*)d_in[11];
  const float* Wno   = (const float*)d_in[12];
  const float* bno   = (const float*)d_in[13];

  const int E = in_sizes[2];   // 800000
  const int N = in_sizes[5];   // 50000
  const int TE = 3, TN = 2;

  char* ws = (char*)d_ws;
  size_t off = 0;
  auto alloc = [&](size_t bytes) -> char* {
    char* p = ws + off;
    off = (off + bytes + 511) & ~(size_t)511;
    return p;
  };
  bf16_t* pW1e  = (bf16_t*)alloc((size_t)TE * 16384 * 2);
  bf16_t* pW1s  = (bf16_t*)alloc((size_t)TE * 16384 * 2);
  bf16_t* pW1d  = (bf16_t*)alloc((size_t)TE * 16384 * 2);
  bf16_t* pWe2  = (bf16_t*)alloc((size_t)TE * 16384 * 2);
  bf16_t* pWn1a = (bf16_t*)alloc((size_t)TN * 16384 * 2);
  bf16_t* pWn1b = (bf16_t*)alloc((size_t)TN * 16384 * 2);
  bf16_t* pWn2  = (bf16_t*)alloc((size_t)TN * 16384 * 2);
  bf16_t* Ps = (bf16_t*)alloc((size_t)TE * N * 128 * 2);
  bf16_t* Pd = (bf16_t*)alloc((size_t)TE * N * 128 * 2);
  bf16_t* Pn = (bf16_t*)alloc((size_t)TN * N * 128 * 2);
  int* rank_e = (int*)alloc((size_t)E * 4);
  int* perm_e = (int*)alloc((size_t)E * 4);
  int* rank_n = (int*)alloc((size_t)N * 4);
  int* perm_n = (int*)alloc((size_t)N * 4);
  const int NBE = (E + RCHUNK - 1) / RCHUNK;   // 196
  const int NBN = (N + RCHUNK - 1) / RCHUNK;   // 13
  int* blkcnt_e  = (int*)alloc((size_t)NBE * TE * 4);
  int* blkbase_e = (int*)alloc((size_t)NBE * TE * 4);
  int* blkcnt_n  = (int*)alloc((size_t)NBN * TN * 4);
  int* blkbase_n = (int*)alloc((size_t)NBN * TN * 4);
  float* agg = (float*)alloc((size_t)N * 128 * 4);
  int* dsthist   = (int*)alloc((size_t)N * 4);
  int* dstoffs   = (int*)alloc((size_t)(N + 1) * 4);
  int* dstcursor = (int*)alloc((size_t)N * 4);
  int* dstpos    = (int*)alloc((size_t)E * 4);
  int4* meta4_e  = (int4*)alloc((size_t)E * 16);
  int*  slotv_e  = (int*)alloc((size_t)E * 4);
  int4* meta4_n  = (int4*)alloc((size_t)N * 16);
  bf16_t* slot_buf = (bf16_t*)alloc((size_t)E * 128 * 2);   // 204.8 MB
  (void)ws_size; (void)n_in; (void)out_size;

  // ---- weight packing & P precompute ----
  pack_w_kernel<<<192, 256, 0, stream>>>(Weh, pW1e, TE, 384, 0, 4);
  pack_w_kernel<<<192, 256, 0, stream>>>(Weh, pW1s, TE, 384, 128, 4);
  pack_w_kernel<<<192, 256, 0, stream>>>(Weh, pW1d, TE, 384, 256, 4);
  pack_w_kernel<<<192, 256, 0, stream>>>(Weo, pWe2, TE, 128, 0, 4);
  pack_w_kernel<<<128, 256, 0, stream>>>(Wnh, pWn1a, TN, 256, 0, 4);
  pack_w_kernel<<<128, 256, 0, stream>>>(Wnh, pWn1b, TN, 256, 128, 4);
  pack_w_kernel<<<128, 256, 0, stream>>>(Wno, pWn2, TN, 128, 0, 4);

  precompute_p_kernel<<<8 * 128, 256, 0, stream>>>(
      nf, pW1s, pW1d, pWn1b, Ps, Pd, Pn, N, 128);

  // ---- type sorts ----
  count_types_kernel<3><<<NBE, 256, 0, stream>>>(etype, E, blkcnt_e);
  scan_blocks_kernel<3><<<1, 256, 0, stream>>>(blkcnt_e, NBE, blkbase_e);
  write_ranks_kernel<3><<<NBE, 256, 0, stream>>>(etype, E, blkbase_e, rank_e, perm_e);

  count_types_kernel<2><<<NBN, 256, 0, stream>>>(ntype, N, blkcnt_n);
  scan_blocks_kernel<2><<<1, 256, 0, stream>>>(blkcnt_n, NBN, blkbase_n);
  write_ranks_kernel<2><<<NBN, 256, 0, stream>>>(ntype, N, blkbase_n, rank_n, perm_n);

  // ---- dst CSR slots ----
  hipMemsetAsync(dsthist, 0, (size_t)N * 4, stream);
  hist_dst_kernel<<<(E + 255) / 256, 256, 0, stream>>>(dst, E, dsthist);
  scan_offsets_kernel<<<1, 1024, 0, stream>>>(dsthist, N, dstoffs, dstcursor);
  scatter_dst_kernel<<<(E + 255) / 256, 256, 0, stream>>>(dst, E, dstcursor, dstpos);

  // ---- flattened meta ----
  gather_meta_edge_kernel<<<(E + 255) / 256, 256, 0, stream>>>(
      perm_e, rank_e, src, dst, dstpos, meta4_e, slotv_e, E);
  gather_meta_node_kernel<<<(N + 255) / 256, 256, 0, stream>>>(
      perm_n, rank_n, meta4_n, N);

  float* out_nf = (float*)d_out;                      // new_nf first
  float* out_ef = (float*)d_out + (size_t)N * 128;    // then new_ef

  // ---- edge MLP (pipelined, no atomics) ----
  mlp5_kernel<3, true><<<512, 256, 0, stream>>>(
      ef, meta4_e, slotv_e, blkbase_e,
      pW1e, beh, pWe2, beo, Ps, Pd, N, out_ef, slot_buf, E);

  // ---- sequential slot aggregation ----
  aggregate_slots_kernel<<<3200, 256, 0, stream>>>(slot_buf, dstoffs, agg, N);

  // ---- node MLP ----
  mlp5_kernel<2, false><<<512, 256, 0, stream>>>(
      agg, meta4_n, nullptr, blkbase_n,
      pWn1a, bnh, pWn2, bno, Pn, nullptr, N, out_nf, nullptr, N);
}